// Round 14
// baseline (5649.068 us; speedup 1.0000x reference)
//
#include <hip/hip_runtime.h>
#include <hip/hip_bf16.h>

typedef unsigned short u16;
typedef unsigned int u32;
typedef __attribute__((ext_vector_type(8))) short short8;
typedef __attribute__((ext_vector_type(4))) float f32x4;

// ---------------- helpers ----------------
__device__ __forceinline__ float bf2f(u16 u) { return __uint_as_float(((u32)u) << 16); }
__device__ __forceinline__ u16 f2bf(float f) {
  u32 x = __float_as_uint(f);
  return (u16)((x + 0x7FFFu + ((x >> 16) & 1u)) >> 16);
}
__device__ __forceinline__ void up4(uint2 r, float* o) {
  o[0] = bf2f((u16)(r.x & 0xFFFF)); o[1] = bf2f((u16)(r.x >> 16));
  o[2] = bf2f((u16)(r.y & 0xFFFF)); o[3] = bf2f((u16)(r.y >> 16));
}
__device__ __forceinline__ uint2 pk4(const float* o) {
  uint2 r;
  r.x = (u32)f2bf(o[0]) | ((u32)f2bf(o[1]) << 16);
  r.y = (u32)f2bf(o[2]) | ((u32)f2bf(o[3]) << 16);
  return r;
}
__device__ __forceinline__ float wsum64(float v) {
#pragma unroll
  for (int o = 32; o > 0; o >>= 1) v += __shfl_xor(v, o, 64);
  return v;
}
__device__ __forceinline__ float sigm(float x) { return 1.0f / (1.0f + __expf(-x)); }

__global__ __launch_bounds__(256) void fill_kernel(float* __restrict__ out, int n, float v) {
  int i = blockIdx.x * 256 + threadIdx.x;
  if (i < n) out[i] = v;
}

// ---------------- weight transpose: in[k][n] f32 -> out[n][k] bf16 ----------------
__global__ __launch_bounds__(256) void wtrans(const float* __restrict__ in,
                                              u16* __restrict__ out, int R, int Ccols) {
  __shared__ float t[64][65];
  const float* ip = in + (size_t)blockIdx.z * R * Ccols;
  u16* op = out + (size_t)blockIdx.z * R * Ccols;
  int kb = blockIdx.x * 64, nb = blockIdx.y * 64;
  int lr = threadIdx.x >> 4, lc = (threadIdx.x & 15) * 4;
#pragma unroll
  for (int p = 0; p < 4; ++p) {
    int k = lr + p * 16;
    float4 v = *(const float4*)(ip + (size_t)(kb + k) * Ccols + nb + lc);
    t[k][lc + 0] = v.x; t[k][lc + 1] = v.y; t[k][lc + 2] = v.z; t[k][lc + 3] = v.w;
  }
  __syncthreads();
#pragma unroll
  for (int p = 0; p < 4; ++p) {
    int n = lr + p * 16;
    uint2 pk;
    pk.x = (u32)f2bf(t[lc + 0][n]) | ((u32)f2bf(t[lc + 1][n]) << 16);
    pk.y = (u32)f2bf(t[lc + 2][n]) | ((u32)f2bf(t[lc + 3][n]) << 16);
    *(uint2*)(op + (size_t)(nb + n) * R + kb + lc) = pk;
  }
}

// ---------------- CSR build ----------------
__global__ __launch_bounds__(256) void csr_hist(const int* __restrict__ dst,
                                                int* __restrict__ hist, int ne) {
  int e = blockIdx.x * 256 + threadIdx.x;
  if (e < ne) atomicAdd(&hist[dst[e]], 1);
}
__global__ __launch_bounds__(1024) void scan1(const int* __restrict__ in,
                                              int* __restrict__ out1, int* __restrict__ bsum, int n) {
  __shared__ int s[1024];
  int i = blockIdx.x * 1024 + threadIdx.x;
  int v = (i < n) ? in[i] : 0;
  s[threadIdx.x] = v; __syncthreads();
  for (int off = 1; off < 1024; off <<= 1) {
    int t = (threadIdx.x >= (u32)off) ? s[threadIdx.x - off] : 0;
    __syncthreads();
    s[threadIdx.x] += t;
    __syncthreads();
  }
  if (i < n) out1[i] = s[threadIdx.x];
  if (threadIdx.x == 1023) bsum[blockIdx.x] = s[1023];
}
__global__ __launch_bounds__(128) void scan2(int* __restrict__ bsum, int nb) {
  __shared__ int s[128];
  int v = (threadIdx.x < (u32)nb) ? bsum[threadIdx.x] : 0;
  s[threadIdx.x] = v; __syncthreads();
  for (int off = 1; off < 128; off <<= 1) {
    int t = (threadIdx.x >= (u32)off) ? s[threadIdx.x - off] : 0;
    __syncthreads();
    s[threadIdx.x] += t;
    __syncthreads();
  }
  if (threadIdx.x < (u32)nb) bsum[threadIdx.x] = threadIdx.x ? s[threadIdx.x - 1] : 0;
}
__global__ __launch_bounds__(256) void scan3(int* __restrict__ offs,
                                             const int* __restrict__ bsum, int n) {
  int i = blockIdx.x * 256 + threadIdx.x;
  if (i == 0) offs[0] = 0;
  if (i < n) offs[1 + i] += bsum[i >> 10];
}
__global__ __launch_bounds__(256) void csr_scatter(const int* __restrict__ dst,
                                                   int* __restrict__ cursor,
                                                   const int* __restrict__ offs,
                                                   int* __restrict__ eid, int ne) {
  int e = blockIdx.x * 256 + threadIdx.x;
  if (e < ne) {
    int d = dst[e];
    int p = offs[d] + atomicAdd(&cursor[d], 1);
    eid[p] = e;
  }
}
__global__ __launch_bounds__(256) void inv_perm(const int* __restrict__ eid,
                                                int* __restrict__ pos, int n) {
  int i = blockIdx.x * 256 + threadIdx.x;
  if (i < n) pos[eid[i]] = i;
}
__global__ __launch_bounds__(256) void remap_k(const int* __restrict__ idx,
                                               const int* __restrict__ map,
                                               int* __restrict__ out, int n) {
  int i = blockIdx.x * 256 + threadIdx.x;
  if (i < n) out[i] = map[idx[i]];
}
__global__ __launch_bounds__(256) void compose_src(const int* __restrict__ eid,
                                                   const int* __restrict__ srcv,
                                                   const int* __restrict__ map,
                                                   int* __restrict__ out, int n) {
  int i = blockIdx.x * 256 + threadIdx.x;
  if (i < n) {
    int s = srcv[eid[i]];
    out[i] = map ? map[s] : s;
  }
}

// ---------------- embeddings ----------------
__global__ __launch_bounds__(256) void embed_s1(
    const float* __restrict__ xin, const float* __restrict__ W1,
    const float* __restrict__ b1, const float* __restrict__ ln1,
    u16* __restrict__ t1, int rows, int bins, float vmin, float vmax,
    const int* __restrict__ perm) {
  int row = (blockIdx.x * 256 + threadIdx.x) >> 6;
  if (row >= rows) return;
  int lane = threadIdx.x & 63;
  float xv = xin[row];
  float rng = vmax - vmin;
  float step = rng / (float)(bins - 1);
  float gamma = 0.5f * ((float)bins / rng) * ((float)bins / rng);
  float rb = 0.f, rb2 = 0.f;
  if (lane < bins) {
    float d = xv - (vmin + lane * step);
    rb = __expf(-gamma * d * d);
  }
  if (bins > 64 && lane < bins - 64) {
    float d = xv - (vmin + (lane + 64) * step);
    rb2 = __expf(-gamma * d * d);
  }
  float u = b1[lane];
  int k1 = bins < 64 ? bins : 64;
  for (int k = 0; k < k1; ++k) {
    float rv = __shfl(rb, k, 64);
    u = fmaf(rv, W1[k * 64 + lane], u);
  }
  for (int k = 64; k < bins; ++k) {
    float rv = __shfl(rb2, k - 64, 64);
    u = fmaf(rv, W1[k * 64 + lane], u);
  }
  float s = wsum64(u), s2 = wsum64(u * u);
  float m = s * (1.f / 64.f), var = s2 * (1.f / 64.f) - m * m;
  float t = (u - m) * rsqrtf(var + 1e-5f) * ln1[lane] + ln1[64 + lane];
  int orow = perm ? perm[row] : row;
  t1[(size_t)orow * 64 + lane] = f2bf(t * sigm(t));
}

__global__ __launch_bounds__(256) void ln_silu(u16* __restrict__ buf,
                                               const float* __restrict__ ln, int rows) {
  int row = (blockIdx.x * 256 + threadIdx.x) >> 6;
  if (row >= rows) return;
  int lane = threadIdx.x & 63;
  int f = lane * 4;
  float v[4];
  up4(*(const uint2*)(buf + (size_t)row * 256 + f), v);
  float s = wsum64(v[0] + v[1] + v[2] + v[3]);
  float s2 = wsum64(v[0] * v[0] + v[1] * v[1] + v[2] * v[2] + v[3] * v[3]);
  float m = s * (1.f / 256.f);
  float rs = rsqrtf(s2 * (1.f / 256.f) - m * m + 1e-5f);
  float o[4];
#pragma unroll
  for (int k = 0; k < 4; ++k) {
    float t = (v[k] - m) * rs * ln[f + k] + ln[256 + f + k];
    o[k] = t * sigm(t);
  }
  *(uint2*)(buf + (size_t)row * 256 + f) = pk4(o);
}

__global__ __launch_bounds__(256) void atom_embed_kernel(
    const float* __restrict__ af, const float* __restrict__ W,
    const float* __restrict__ b, const float* __restrict__ ln,
    u16* __restrict__ out, int rows) {
  int row = blockIdx.x;
  if (row >= rows) return;
  __shared__ float a_s[92];
  __shared__ float red[8];
  int tid = threadIdx.x;
  if (tid < 92) a_s[tid] = af[(size_t)row * 92 + tid];
  __syncthreads();
  float v = b[tid];
#pragma unroll 4
  for (int k = 0; k < 92; ++k) v = fmaf(a_s[k], W[k * 256 + tid], v);
  float s = wsum64(v), s2 = wsum64(v * v);
  int lane = tid & 63, wid = tid >> 6;
  if (lane == 0) { red[wid] = s; red[4 + wid] = s2; }
  __syncthreads();
  s = red[0] + red[1] + red[2] + red[3];
  s2 = red[4] + red[5] + red[6] + red[7];
  float m = s * (1.f / 256.f), var = s2 * (1.f / 256.f) - m * m;
  float t = (v - m) * rsqrtf(var + 1e-5f) * ln[tid] + ln[256 + tid];
  out[(size_t)row * 256 + tid] = f2bf(t * sigm(t));
}

// ---------------- MFMA GEMM: C[M,ldc](bf16) = A[M,K](bf16) @ W + bias ----------------
// smap: packed slab indices (8 bits per 256-col block)
__global__ __launch_bounds__(256) void mfma_gemm(
    const u16* __restrict__ A, const u16* __restrict__ Wt,
    const float* __restrict__ bias, u16* __restrict__ C,
    int M, int K, int ldc, u32 smap) {
  int bm = blockIdx.x * 128;
  if (bm >= M) return;
  int bn = blockIdx.y * 128;
  int slab = (smap >> ((bn >> 8) * 8)) & 0xFF;
  const u16* Wp = Wt + (size_t)slab * 256 * K + (size_t)(bn & 255) * K;
  const float* bp = bias + slab * 256 + (bn & 255);
  int tid = threadIdx.x;
  int w = tid >> 6, lane = tid & 63;
  int q = lane >> 4, r = lane & 15;
  int m0 = (w & 1) * 64;
  int n0 = (w >> 1) * 64;
  const u16* aptr[4];
#pragma unroll
  for (int mi = 0; mi < 4; ++mi) {
    int m = bm + m0 + mi * 16 + r;
    m = m < M - 1 ? m : M - 1;
    aptr[mi] = A + (size_t)m * K + q * 8;
  }
  const u16* wptr[4];
#pragma unroll
  for (int ni = 0; ni < 4; ++ni)
    wptr[ni] = Wp + (size_t)(n0 + ni * 16 + r) * K + q * 8;
  f32x4 acc[4][4] = {};
  for (int kb = 0; kb < K; kb += 32) {
    short8 bfr[4], afr[4];
#pragma unroll
    for (int mi = 0; mi < 4; ++mi) bfr[mi] = *(const short8*)(aptr[mi] + kb);
#pragma unroll
    for (int ni = 0; ni < 4; ++ni) afr[ni] = *(const short8*)(wptr[ni] + kb);
#pragma unroll
    for (int mi = 0; mi < 4; ++mi)
#pragma unroll
      for (int ni = 0; ni < 4; ++ni)
        acc[mi][ni] = __builtin_amdgcn_mfma_f32_16x16x32_bf16(afr[ni], bfr[mi],
                                                              acc[mi][ni], 0, 0, 0);
  }
#pragma unroll
  for (int mi = 0; mi < 4; ++mi) {
    int m = bm + m0 + mi * 16 + r;
    if (m < M) {
#pragma unroll
      for (int ni = 0; ni < 4; ++ni) {
        int n = n0 + ni * 16 + q * 4;
        float4 bv = *(const float4*)(bp + n);
        uint2 o;
        o.x = (u32)f2bf(acc[mi][ni].x + bv.x) | ((u32)f2bf(acc[mi][ni].y + bv.y) << 16);
        o.y = (u32)f2bf(acc[mi][ni].z + bv.z) | ((u32)f2bf(acc[mi][ni].w + bv.w) << 16);
        *(uint2*)(C + (size_t)m * ldc + bn + n) = o;
      }
    }
  }
}

// ---------------- mega_line: 16 dst, 512 thr; full-wave rows, dual-chain interleaved C ----
__global__ __launch_bounds__(512) void mega_line(
    u16* __restrict__ h, u16* __restrict__ e, const u16* __restrict__ G0Bh,
    const u16* __restrict__ Wt13, const float* __restrict__ b13,
    const u16* __restrict__ Wt2, const float* __restrict__ b2v,
    const int* __restrict__ src_perm, const int* __restrict__ offs,
    const float* __restrict__ lnS, const float* __restrict__ lnB, int nn) {
  __shared__ u16 g1ah[16][520];
  __shared__ u16 pe[64][264];
  __shared__ int oloc[17];
  int tid = threadIdx.x;
  int w = tid >> 6, lane = tid & 63;
  int q = lane >> 4, r = lane & 15;
  int v0 = blockIdx.x * 16;
  if (tid < 17) { int v = v0 + tid; oloc[tid] = offs[v < nn ? v : nn]; }
  // ---- Phase A: g1ah[16][512] = h[v0..v0+16) @ [W1|W3] + b ----
  {
    int mrow = v0 + r; if (mrow > nn - 1) mrow = nn - 1;
    const u16* arow = h + (size_t)mrow * 256 + q * 8;
    f32x4 acc[4] = {};
    for (int kb = 0; kb < 256; kb += 32) {
      short8 af = *(const short8*)(arow + kb);
#pragma unroll
      for (int t = 0; t < 4; ++t) {
        int ng = (4 * w + t) * 16 + r;
        const u16* wrow = Wt13 + (size_t)(ng >> 8) * 2 * 65536 +
                          (size_t)(ng & 255) * 256 + q * 8;
        short8 wf = *(const short8*)(wrow + kb);
        acc[t] = __builtin_amdgcn_mfma_f32_16x16x32_bf16(wf, af, acc[t], 0, 0, 0);
      }
    }
#pragma unroll
    for (int t = 0; t < 4; ++t) {
      int nb = (4 * w + t) * 16 + q * 4;
      const float* bp = b13 + (nb >> 8) * 2 * 256 + (nb & 255);
      float o[4] = {acc[t].x + bp[0], acc[t].y + bp[1], acc[t].z + bp[2], acc[t].w + bp[3]};
      *(uint2*)&g1ah[r][nb] = pk4(o);
    }
  }
  __syncthreads();
  int f = lane * 4;
  int r0 = oloc[0], r1 = oloc[16];
  int eA0 = oloc[2 * w], eA1 = oloc[2 * w + 1];
  int eB0 = oloc[2 * w + 1], eB1 = oloc[2 * w + 2];
  float sshA[4] = {}, ssmA[4] = {}, sshB[4] = {}, ssmB[4] = {};
  float lwe[4], lbe[4];
#pragma unroll
  for (int k = 0; k < 4; ++k) { lwe[k] = lnS[f + k]; lbe[k] = lnB[f + k]; }
  float g1A[4], g1Bv[4];
  up4(*(const uint2*)&g1ah[2 * w][f], g1A);
  up4(*(const uint2*)&g1ah[2 * w + 1][f], g1Bv);

  for (int ec = r0; ec < r1; ec += 64) {
    // ---- Phase B: pe[0..64) = e[ec..ec+64) @ W2 + b2 ----
    {
      const u16* w0p = Wt2 + (size_t)((2 * w) * 16 + r) * 256 + q * 8;
      const u16* w1p = Wt2 + (size_t)((2 * w + 1) * 16 + r) * 256 + q * 8;
      f32x4 acc[4][2] = {};
      for (int kb = 0; kb < 256; kb += 32) {
        short8 wf0 = *(const short8*)(w0p + kb);
        short8 wf1 = *(const short8*)(w1p + kb);
#pragma unroll
        for (int mt = 0; mt < 4; ++mt) {
          int erow = ec + mt * 16 + r;
          if (erow > r1 - 1) erow = r1 - 1;
          short8 af = *(const short8*)(e + (size_t)erow * 256 + kb + q * 8);
          acc[mt][0] = __builtin_amdgcn_mfma_f32_16x16x32_bf16(wf0, af, acc[mt][0], 0, 0, 0);
          acc[mt][1] = __builtin_amdgcn_mfma_f32_16x16x32_bf16(wf1, af, acc[mt][1], 0, 0, 0);
        }
      }
#pragma unroll
      for (int mt = 0; mt < 4; ++mt)
#pragma unroll
        for (int nt = 0; nt < 2; ++nt) {
          int nb = (2 * w + nt) * 16 + q * 4;
          float o[4] = {acc[mt][nt].x + b2v[nb], acc[mt][nt].y + b2v[nb + 1],
                        acc[mt][nt].z + b2v[nb + 2], acc[mt][nt].w + b2v[nb + 3]};
          *(uint2*)&pe[mt * 16 + r][nb] = pk4(o);
        }
    }
    __syncthreads();
    // ---- Phase C: dual-chain interleave (dst A and dst B), 1-deep prefetch ----
    {
      int ce = ec + 64 < r1 ? ec + 64 : r1;
      int ia = eA0 > ec ? eA0 : ec, iaE = eA1 < ce ? eA1 : ce;
      int ib = eB0 > ec ? eB0 : ec, ibE = eB1 < ce ? eB1 : ce;
      uint2 ag0, abh, aev, bg0, bbh, bev;
      if (ia < iaE) {
        int sv = src_perm[ia];
        ag0 = *(const uint2*)(G0Bh + (size_t)sv * 512 + f);
        abh = *(const uint2*)(G0Bh + (size_t)sv * 512 + 256 + f);
        aev = *(const uint2*)(e + (size_t)ia * 256 + f);
      }
      if (ib < ibE) {
        int sv = src_perm[ib];
        bg0 = *(const uint2*)(G0Bh + (size_t)sv * 512 + f);
        bbh = *(const uint2*)(G0Bh + (size_t)sv * 512 + 256 + f);
        bev = *(const uint2*)(e + (size_t)ib * 256 + f);
      }
      while (ia < iaE || ib < ibE) {
        uint2 nag0, nabh, naev, nbg0, nbbh, nbev;
        if (ia + 1 < iaE) {
          int sv = src_perm[ia + 1];
          nag0 = *(const uint2*)(G0Bh + (size_t)sv * 512 + f);
          nabh = *(const uint2*)(G0Bh + (size_t)sv * 512 + 256 + f);
          naev = *(const uint2*)(e + (size_t)(ia + 1) * 256 + f);
        }
        if (ib + 1 < ibE) {
          int sv = src_perm[ib + 1];
          nbg0 = *(const uint2*)(G0Bh + (size_t)sv * 512 + f);
          nbbh = *(const uint2*)(G0Bh + (size_t)sv * 512 + 256 + f);
          nbev = *(const uint2*)(e + (size_t)(ib + 1) * 256 + f);
        }
        if (ia < iaE) {
          float g0v[4], bhv[4], pv[4], ev[4], t[4];
          up4(ag0, g0v); up4(abh, bhv); up4(aev, ev);
          up4(*(const uint2*)&pe[ia - ec][f], pv);
          float ssum = 0.f, s2sum = 0.f;
#pragma unroll
          for (int k = 0; k < 4; ++k) {
            float sg = sigm(g0v[k] + g1A[k] + pv[k]);
            t[k] = sg * ev[k];
            sshA[k] = fmaf(bhv[k], sg, sshA[k]);
            ssmA[k] += sg;
            ssum += t[k]; s2sum += t[k] * t[k];
          }
          float s1 = wsum64(ssum), s2 = wsum64(s2sum);
          float mn = s1 * (1.f / 256.f);
          float rs = rsqrtf(s2 * (1.f / 256.f) - mn * mn + 1e-5f);
          float o[4];
#pragma unroll
          for (int k = 0; k < 4; ++k) o[k] = (t[k] - mn) * rs * lwe[k] + lbe[k];
          *(uint2*)(e + (size_t)ia * 256 + f) = pk4(o);
        }
        if (ib < ibE) {
          float g0v[4], bhv[4], pv[4], ev[4], t[4];
          up4(bg0, g0v); up4(bbh, bhv); up4(bev, ev);
          up4(*(const uint2*)&pe[ib - ec][f], pv);
          float ssum = 0.f, s2sum = 0.f;
#pragma unroll
          for (int k = 0; k < 4; ++k) {
            float sg = sigm(g0v[k] + g1Bv[k] + pv[k]);
            t[k] = sg * ev[k];
            sshB[k] = fmaf(bhv[k], sg, sshB[k]);
            ssmB[k] += sg;
            ssum += t[k]; s2sum += t[k] * t[k];
          }
          float s1 = wsum64(ssum), s2 = wsum64(s2sum);
          float mn = s1 * (1.f / 256.f);
          float rs = rsqrtf(s2 * (1.f / 256.f) - mn * mn + 1e-5f);
          float o[4];
#pragma unroll
          for (int k = 0; k < 4; ++k) o[k] = (t[k] - mn) * rs * lwe[k] + lbe[k];
          *(uint2*)(e + (size_t)ib * 256 + f) = pk4(o);
        }
        ag0 = nag0; abh = nabh; aev = naev;
        bg0 = nbg0; bbh = nbbh; bev = nbev;
        ia += (ia < iaE) ? 1 : 0;
        ib += (ib < ibE) ? 1 : 0;
      }
    }
    __syncthreads();
  }
  // ---- Phase D ----
#pragma unroll
  for (int jj = 0; jj < 2; ++jj) {
    int vv = v0 + 2 * w + jj;
    if (vv < nn) {
      float ah[4], tt[4];
      up4(*(const uint2*)&g1ah[2 * w + jj][256 + f], ah);
      float ssum = 0.f, s2sum = 0.f;
#pragma unroll
      for (int k = 0; k < 4; ++k) {
        float sh = jj ? sshB[k] : sshA[k];
        float sm = jj ? ssmB[k] : ssmA[k];
        tt[k] = ah[k] + sh / (sm + 1e-8f);
        ssum += tt[k]; s2sum += tt[k] * tt[k];
      }
      float s1 = wsum64(ssum), s2 = wsum64(s2sum);
      float mn = s1 * (1.f / 256.f);
      float rs = rsqrtf(s2 * (1.f / 256.f) - mn * mn + 1e-5f);
      float o[4];
#pragma unroll
      for (int k = 0; k < 4; ++k)
        o[k] = (tt[k] - mn) * rs * lnS[256 + f + k] + lnB[256 + f + k];
      *(uint2*)(h + (size_t)vv * 256 + f) = pk4(o);
    }
  }
}

// ---------------- mega_atom: 16 dst, 512 thr; GAll precomputed, dual-chain C ----------------
__global__ __launch_bounds__(512) void mega_atom(
    u16* __restrict__ h, u16* __restrict__ e, const u16* __restrict__ GAll,
    const u16* __restrict__ Wt2, const float* __restrict__ b2v,
    const int* __restrict__ src_perm, const int* __restrict__ offs,
    const float* __restrict__ lnS, const float* __restrict__ lnB, int nn) {
  __shared__ u16 pe[64][264];
  __shared__ int oloc[17];
  int tid = threadIdx.x;
  int w = tid >> 6, lane = tid & 63;
  int q = lane >> 4, r = lane & 15;
  int v0 = blockIdx.x * 16;
  if (tid < 17) { int v = v0 + tid; oloc[tid] = offs[v < nn ? v : nn]; }
  __syncthreads();
  int f = lane * 4;
  int r0 = oloc[0], r1 = oloc[16];
  int eA0 = oloc[2 * w], eA1 = oloc[2 * w + 1];
  int eB0 = oloc[2 * w + 1], eB1 = oloc[2 * w + 2];
  float sshA[4] = {}, ssmA[4] = {}, sshB[4] = {}, ssmB[4] = {};
  float lwe[4], lbe[4];
#pragma unroll
  for (int k = 0; k < 4; ++k) { lwe[k] = lnS[f + k]; lbe[k] = lnB[f + k]; }
  int vAc = v0 + 2 * w;     if (vAc > nn - 1) vAc = nn - 1;
  int vBc = v0 + 2 * w + 1; if (vBc > nn - 1) vBc = nn - 1;
  float g1A[4], g1Bv[4];
  up4(*(const uint2*)(GAll + (size_t)vAc * 1024 + 256 + f), g1A);
  up4(*(const uint2*)(GAll + (size_t)vBc * 1024 + 256 + f), g1Bv);

  for (int ec = r0; ec < r1; ec += 64) {
    // ---- Phase B ----
    {
      const u16* w0p = Wt2 + (size_t)((2 * w) * 16 + r) * 256 + q * 8;
      const u16* w1p = Wt2 + (size_t)((2 * w + 1) * 16 + r) * 256 + q * 8;
      f32x4 acc[4][2] = {};
      for (int kb = 0; kb < 256; kb += 32) {
        short8 wf0 = *(const short8*)(w0p + kb);
        short8 wf1 = *(const short8*)(w1p + kb);
#pragma unroll
        for (int mt = 0; mt < 4; ++mt) {
          int erow = ec + mt * 16 + r;
          if (erow > r1 - 1) erow = r1 - 1;
          short8 af = *(const short8*)(e + (size_t)erow * 256 + kb + q * 8);
          acc[mt][0] = __builtin_amdgcn_mfma_f32_16x16x32_bf16(wf0, af, acc[mt][0], 0, 0, 0);
          acc[mt][1] = __builtin_amdgcn_mfma_f32_16x16x32_bf16(wf1, af, acc[mt][1], 0, 0, 0);
        }
      }
#pragma unroll
      for (int mt = 0; mt < 4; ++mt)
#pragma unroll
        for (int nt = 0; nt < 2; ++nt) {
          int nb = (2 * w + nt) * 16 + q * 4;
          float o[4] = {acc[mt][nt].x + b2v[nb], acc[mt][nt].y + b2v[nb + 1],
                        acc[mt][nt].z + b2v[nb + 2], acc[mt][nt].w + b2v[nb + 3]};
          *(uint2*)&pe[mt * 16 + r][nb] = pk4(o);
        }
    }
    __syncthreads();
    // ---- Phase C: dual-chain interleave with GAll gathers ----
    {
      int ce = ec + 64 < r1 ? ec + 64 : r1;
      int ia = eA0 > ec ? eA0 : ec, iaE = eA1 < ce ? eA1 : ce;
      int ib = eB0 > ec ? eB0 : ec, ibE = eB1 < ce ? eB1 : ce;
      uint2 ag0, abh, aev, bg0, bbh, bev;
      if (ia < iaE) {
        int sv = src_perm[ia];
        ag0 = *(const uint2*)(GAll + (size_t)sv * 1024 + f);
        abh = *(const uint2*)(GAll + (size_t)sv * 1024 + 768 + f);
        aev = *(const uint2*)(e + (size_t)ia * 256 + f);
      }
      if (ib < ibE) {
        int sv = src_perm[ib];
        bg0 = *(const uint2*)(GAll + (size_t)sv * 1024 + f);
        bbh = *(const uint2*)(GAll + (size_t)sv * 1024 + 768 + f);
        bev = *(const uint2*)(e + (size_t)ib * 256 + f);
      }
      while (ia < iaE || ib < ibE) {
        uint2 nag0, nabh, naev, nbg0, nbbh, nbev;
        if (ia + 1 < iaE) {
          int sv = src_perm[ia + 1];
          nag0 = *(const uint2*)(GAll + (size_t)sv * 1024 + f);
          nabh = *(const uint2*)(GAll + (size_t)sv * 1024 + 768 + f);
          naev = *(const uint2*)(e + (size_t)(ia + 1) * 256 + f);
        }
        if (ib + 1 < ibE) {
          int sv = src_perm[ib + 1];
          nbg0 = *(const uint2*)(GAll + (size_t)sv * 1024 + f);
          nbbh = *(const uint2*)(GAll + (size_t)sv * 1024 + 768 + f);
          nbev = *(const uint2*)(e + (size_t)(ib + 1) * 256 + f);
        }
        if (ia < iaE) {
          float g0v[4], bhv[4], pv[4], ev[4], t[4];
          up4(ag0, g0v); up4(abh, bhv); up4(aev, ev);
          up4(*(const uint2*)&pe[ia - ec][f], pv);
          float ssum = 0.f, s2sum = 0.f;
#pragma unroll
          for (int k = 0; k < 4; ++k) {
            float sg = sigm(g0v[k] + g1A[k] + pv[k]);
            t[k] = sg * ev[k];
            sshA[k] = fmaf(bhv[k], sg, sshA[k]);
            ssmA[k] += sg;
            ssum += t[k]; s2sum += t[k] * t[k];
          }
          float s1 = wsum64(ssum), s2 = wsum64(s2sum);
          float mn = s1 * (1.f / 256.f);
          float rs = rsqrtf(s2 * (1.f / 256.f) - mn * mn + 1e-5f);
          float o[4];
#pragma unroll
          for (int k = 0; k < 4; ++k) o[k] = (t[k] - mn) * rs * lwe[k] + lbe[k];
          *(uint2*)(e + (size_t)ia * 256 + f) = pk4(o);
        }
        if (ib < ibE) {
          float g0v[4], bhv[4], pv[4], ev[4], t[4];
          up4(bg0, g0v); up4(bbh, bhv); up4(bev, ev);
          up4(*(const uint2*)&pe[ib - ec][f], pv);
          float ssum = 0.f, s2sum = 0.f;
#pragma unroll
          for (int k = 0; k < 4; ++k) {
            float sg = sigm(g0v[k] + g1Bv[k] + pv[k]);
            t[k] = sg * ev[k];
            sshB[k] = fmaf(bhv[k], sg, sshB[k]);
            ssmB[k] += sg;
            ssum += t[k]; s2sum += t[k] * t[k];
          }
          float s1 = wsum64(ssum), s2 = wsum64(s2sum);
          float mn = s1 * (1.f / 256.f);
          float rs = rsqrtf(s2 * (1.f / 256.f) - mn * mn + 1e-5f);
          float o[4];
#pragma unroll
          for (int k = 0; k < 4; ++k) o[k] = (t[k] - mn) * rs * lwe[k] + lbe[k];
          *(uint2*)(e + (size_t)ib * 256 + f) = pk4(o);
        }
        ag0 = nag0; abh = nabh; aev = naev;
        bg0 = nbg0; bbh = nbbh; bev = nbev;
        ia += (ia < iaE) ? 1 : 0;
        ib += (ib < ibE) ? 1 : 0;
      }
    }
    __syncthreads();
  }
  // ---- Phase D ----
#pragma unroll
  for (int jj = 0; jj < 2; ++jj) {
    int vv = v0 + 2 * w + jj;
    if (vv < nn) {
      float ah[4], tt[4];
      up4(*(const uint2*)(GAll + (size_t)vv * 1024 + 512 + f), ah);
      float ssum = 0.f, s2sum = 0.f;
#pragma unroll
      for (int k = 0; k < 4; ++k) {
        float sh = jj ? sshB[k] : sshA[k];
        float sm = jj ? ssmB[k] : ssmA[k];
        tt[k] = ah[k] + sh / (sm + 1e-8f);
        ssum += tt[k]; s2sum += tt[k] * tt[k];
      }
      float s1 = wsum64(ssum), s2 = wsum64(s2sum);
      float mn = s1 * (1.f / 256.f);
      float rs = rsqrtf(s2 * (1.f / 256.f) - mn * mn + 1e-5f);
      float o[4];
#pragma unroll
      for (int k = 0; k < 4; ++k)
        o[k] = (tt[k] - mn) * rs * lnS[256 + f + k] + lnB[256 + f + k];
      *(uint2*)(h + (size_t)vv * 256 + f) = pk4(o);
    }
  }
}

// ---------------- readout ----------------
__global__ __launch_bounds__(256) void pool_acc(
    const u16* __restrict__ x, const int* __restrict__ gid,
    float* __restrict__ out, float* __restrict__ cnt, int n) {
  int v = (blockIdx.x * 256 + threadIdx.x) >> 6;
  if (v >= n) return;
  int lane = threadIdx.x & 63;
  int f = lane * 4;
  int g = gid[v];
  float xv[4];
  up4(*(const uint2*)(x + (size_t)v * 256 + f), xv);
  float* p = out + (size_t)g * 256 + f;
  unsafeAtomicAdd(p + 0, xv[0]);
  unsafeAtomicAdd(p + 1, xv[1]);
  unsafeAtomicAdd(p + 2, xv[2]);
  unsafeAtomicAdd(p + 3, xv[3]);
  if (lane == 0) unsafeAtomicAdd(cnt + g, 1.0f);
}
__global__ __launch_bounds__(256) void pool_div(float* __restrict__ out,
                                                const float* __restrict__ cnt, int n) {
  int i = blockIdx.x * blockDim.x + threadIdx.x;
  if (i < n) out[i] /= fmaxf(cnt[i >> 8], 1.0f);
}

// ---------------- host ----------------
extern "C" void kernel_launch(void* const* d_in, const int* in_sizes, int n_in,
                              void* d_out, int out_size, void* d_ws, size_t ws_size,
                              hipStream_t stream) {
  const float* atom_features = (const float*)d_in[0];
  const float* bondlength    = (const float*)d_in[1];
  const float* angle_h       = (const float*)d_in[2];
  const int*   src           = (const int*)d_in[3];
  const int*   dst           = (const int*)d_in[4];
  const int*   lg_src        = (const int*)d_in[5];
  const int*   lg_dst        = (const int*)d_in[6];
  const int*   gid           = (const int*)d_in[7];
  const float* atom_W  = (const float*)d_in[8];
  const float* atom_b  = (const float*)d_in[9];
  const float* atom_ln = (const float*)d_in[10];
  const float* edge_W1 = (const float*)d_in[11];
  const float* edge_b1 = (const float*)d_in[12];
  const float* edge_ln1= (const float*)d_in[13];
  const float* edge_W2 = (const float*)d_in[14];
  const float* edge_b2 = (const float*)d_in[15];
  const float* edge_ln2= (const float*)d_in[16];
  const float* ang_W1  = (const float*)d_in[17];
  const float* ang_b1  = (const float*)d_in[18];
  const float* ang_ln1 = (const float*)d_in[19];
  const float* ang_W2  = (const float*)d_in[20];
  const float* ang_b2  = (const float*)d_in[21];
  const float* ang_ln2 = (const float*)d_in[22];
  const float* conv_W  = (const float*)d_in[23];
  const float* conv_b  = (const float*)d_in[24];
  const float* conv_lns= (const float*)d_in[25];
  const float* conv_lnb= (const float*)d_in[26];

  int N = in_sizes[0] / 92;
  int E = in_sizes[1];
  int T = in_sizes[2];

  // ---- workspace layout ----
  char* ws = (char*)d_ws;
  size_t o = 0;
  auto alloc = [&](size_t bytes) { size_t r = o; o = (o + bytes + 255) & ~(size_t)255; return r; };
  u16* z     = (u16*)(ws + alloc((size_t)T * 512));
  u16* y     = (u16*)(ws + alloc((size_t)E * 512));
  u16* x     = (u16*)(ws + alloc((size_t)N * 512));
  int* offsL = (int*)(ws + alloc((size_t)(E + 1) * 4));
  int* offsA = (int*)(ws + alloc((size_t)(N + 1) * 4));
  int* spL   = (int*)(ws + alloc((size_t)T * 4));
  int* spA   = (int*)(ws + alloc((size_t)E * 4));
  int* pA    = (int*)(ws + alloc((size_t)E * 4));
  int* pL    = (int*)(ws + alloc((size_t)T * 4));
  int* eidL  = (int*)(ws + alloc((size_t)T * 4));
  int* eidA  = (int*)(ws + alloc((size_t)E * 4));
  int* ldSt  = (int*)(ws + alloc((size_t)T * 4));
  int* tmp   = (int*)(ws + alloc((size_t)(E > N ? E : N) * 4));
  int* bsum  = (int*)(ws + alloc(1024));
  float* cnt = (float*)(ws + alloc(1024));
  u16* WtAll = (u16*)(ws + alloc((size_t)12 * 5 * 65536 * 2));
  u16* WtAng = (u16*)(ws + alloc((size_t)16384 * 2));
  u16* WtEdg = (u16*)(ws + alloc((size_t)16384 * 2));
  size_t scratch_base = o;
  size_t need = scratch_base + (size_t)E * 1024;  // line G0Bh dominant
  {
    size_t embed_need = scratch_base + ((size_t)T + E) * 128;
    if (embed_need > need) need = embed_need;
  }
  if (ws_size < need) {
    fill_kernel<<<(out_size + 255) / 256, 256, 0, stream>>>(
        (float*)d_out, out_size, (float)(ws_size >> 20));
    return;
  }

  // ---- weight transposes ----
  wtrans<<<dim3(4, 4, 60), 256, 0, stream>>>(conv_W, WtAll, 256, 256);
  wtrans<<<dim3(1, 4, 1), 256, 0, stream>>>(ang_W2, WtAng, 64, 256);
  wtrans<<<dim3(1, 4, 1), 256, 0, stream>>>(edge_W2, WtEdg, 64, 256);

  // ---- CSR + permutations ----
  auto build_csr = [&](const int* dvec, int ne_, int nn_, int* offs_, int* eid_) {
    hipMemsetAsync(tmp, 0, (size_t)nn_ * 4, stream);
    csr_hist<<<(ne_ + 255) / 256, 256, 0, stream>>>(dvec, tmp, ne_);
    int nb = (nn_ + 1023) / 1024;
    scan1<<<nb, 1024, 0, stream>>>(tmp, offs_ + 1, bsum, nn_);
    scan2<<<1, 128, 0, stream>>>(bsum, nb);
    scan3<<<(nn_ + 255) / 256, 256, 0, stream>>>(offs_, bsum, nn_);
    hipMemsetAsync(tmp, 0, (size_t)nn_ * 4, stream);
    csr_scatter<<<(ne_ + 255) / 256, 256, 0, stream>>>(dvec, tmp, offs_, eid_, ne_);
  };
  build_csr(dst, E, N, offsA, eidA);
  inv_perm<<<(E + 255) / 256, 256, 0, stream>>>(eidA, pA, E);
  compose_src<<<(E + 255) / 256, 256, 0, stream>>>(eidA, src, nullptr, spA, E);
  remap_k<<<(T + 255) / 256, 256, 0, stream>>>(lg_dst, pA, ldSt, T);
  build_csr(ldSt, T, E, offsL, eidL);
  inv_perm<<<(T + 255) / 256, 256, 0, stream>>>(eidL, pL, T);
  compose_src<<<(T + 255) / 256, 256, 0, stream>>>(eidL, lg_src, pA, spL, T);

  // ---- embeddings ----
  u16* t1T = (u16*)(ws + scratch_base);
  u16* t1E = t1T + (size_t)T * 64;
  embed_s1<<<(T + 3) / 4, 256, 0, stream>>>(angle_h, ang_W1, ang_b1, ang_ln1,
                                            t1T, T, 40, -1.f, 1.f, pL);
  embed_s1<<<(E + 3) / 4, 256, 0, stream>>>(bondlength, edge_W1, edge_b1, edge_ln1,
                                            t1E, E, 80, 0.f, 8.f, pA);
  mfma_gemm<<<dim3((T + 127) / 128, 2), 256, 0, stream>>>(
      t1T, WtAng, ang_b2, z, T, 64, 256, 0u);
  mfma_gemm<<<dim3((E + 127) / 128, 2), 256, 0, stream>>>(
      t1E, WtEdg, edge_b2, y, E, 64, 256, 0u);
  ln_silu<<<(T + 3) / 4, 256, 0, stream>>>(z, ang_ln2, T);
  ln_silu<<<(E + 3) / 4, 256, 0, stream>>>(y, edge_ln2, E);
  atom_embed_kernel<<<N, 256, 0, stream>>>(atom_features, atom_W, atom_b, atom_ln, x, N);

  // ---- 12 EGGC layers ----
  for (int l = 0; l < 12; ++l) {
    const u16* WtL  = WtAll + (size_t)l * 5 * 65536;
    const float* bl = conv_b + (size_t)l * 5 * 256;
    const float* lnS = conv_lns + (size_t)l * 512;
    const float* lnB = conv_lnb + (size_t)l * 512;
    bool line = (l < 8) && ((l & 1) == 0);
    if (line) {
      u16* G0Bh = (u16*)(ws + scratch_base);
      mfma_gemm<<<dim3((E + 127) / 128, 4), 256, 0, stream>>>(
          y, WtL, bl, G0Bh, E, 256, 512, 0u | (4u << 8));
      mega_line<<<(E + 15) / 16, 512, 0, stream>>>(
          y, z, G0Bh, WtL + 65536, bl + 256, WtL + 2 * 65536, bl + 2 * 256,
          spL, offsL, lnS, lnB, E);
    } else {
      u16* GAll = (u16*)(ws + scratch_base);
      mfma_gemm<<<dim3((N + 127) / 128, 8), 256, 0, stream>>>(
          x, WtL, bl, GAll, N, 256, 1024, 0u | (1u << 8) | (3u << 16) | (4u << 24));
      mega_atom<<<(N + 15) / 16, 512, 0, stream>>>(
          x, y, GAll, WtL + 2 * 65536, bl + 2 * 256,
          spA, offsA, lnS, lnB, N);
    }
  }

  // ---- readout ----
  hipMemsetAsync(d_out, 0, (size_t)out_size * sizeof(float), stream);
  hipMemsetAsync(cnt, 0, 256 * sizeof(float), stream);
  pool_acc<<<(N + 3) / 4, 256, 0, stream>>>(x, gid, (float*)d_out, cnt, N);
  pool_div<<<(out_size + 255) / 256, 256, 0, stream>>>((float*)d_out, cnt, out_size);
}

// Round 16
// 4663.352 us; speedup vs baseline: 1.2114x; 1.2114x over previous
//
#include <hip/hip_runtime.h>
#include <hip/hip_bf16.h>

typedef unsigned short u16;
typedef unsigned int u32;
typedef __attribute__((ext_vector_type(8))) short short8;
typedef __attribute__((ext_vector_type(4))) float f32x4;

// ---------------- helpers ----------------
__device__ __forceinline__ float bf2f(u16 u) { return __uint_as_float(((u32)u) << 16); }
__device__ __forceinline__ u16 f2bf(float f) {
  u32 x = __float_as_uint(f);
  return (u16)((x + 0x7FFFu + ((x >> 16) & 1u)) >> 16);
}
__device__ __forceinline__ void up4(uint2 r, float* o) {
  o[0] = bf2f((u16)(r.x & 0xFFFF)); o[1] = bf2f((u16)(r.x >> 16));
  o[2] = bf2f((u16)(r.y & 0xFFFF)); o[3] = bf2f((u16)(r.y >> 16));
}
__device__ __forceinline__ uint2 pk4(const float* o) {
  uint2 r;
  r.x = (u32)f2bf(o[0]) | ((u32)f2bf(o[1]) << 16);
  r.y = (u32)f2bf(o[2]) | ((u32)f2bf(o[3]) << 16);
  return r;
}
__device__ __forceinline__ void up8(uint4 r, float* o) {
  o[0] = bf2f((u16)(r.x & 0xFFFF)); o[1] = bf2f((u16)(r.x >> 16));
  o[2] = bf2f((u16)(r.y & 0xFFFF)); o[3] = bf2f((u16)(r.y >> 16));
  o[4] = bf2f((u16)(r.z & 0xFFFF)); o[5] = bf2f((u16)(r.z >> 16));
  o[6] = bf2f((u16)(r.w & 0xFFFF)); o[7] = bf2f((u16)(r.w >> 16));
}
__device__ __forceinline__ uint4 pk8(const float* o) {
  uint4 r;
  r.x = (u32)f2bf(o[0]) | ((u32)f2bf(o[1]) << 16);
  r.y = (u32)f2bf(o[2]) | ((u32)f2bf(o[3]) << 16);
  r.z = (u32)f2bf(o[4]) | ((u32)f2bf(o[5]) << 16);
  r.w = (u32)f2bf(o[6]) | ((u32)f2bf(o[7]) << 16);
  return r;
}
__device__ __forceinline__ float wsum64(float v) {
#pragma unroll
  for (int o = 32; o > 0; o >>= 1) v += __shfl_xor(v, o, 64);
  return v;
}
__device__ __forceinline__ float wsum16(float v) {
#pragma unroll
  for (int o = 8; o > 0; o >>= 1) v += __shfl_xor(v, o, 64);
  return v;
}
__device__ __forceinline__ float sigm(float x) { return 1.0f / (1.0f + __expf(-x)); }

__global__ __launch_bounds__(256) void fill_kernel(float* __restrict__ out, int n, float v) {
  int i = blockIdx.x * 256 + threadIdx.x;
  if (i < n) out[i] = v;
}

// ---------------- weight transpose: in[k][n] f32 -> out[n][k] bf16 ----------------
__global__ __launch_bounds__(256) void wtrans(const float* __restrict__ in,
                                              u16* __restrict__ out, int R, int Ccols) {
  __shared__ float t[64][65];
  const float* ip = in + (size_t)blockIdx.z * R * Ccols;
  u16* op = out + (size_t)blockIdx.z * R * Ccols;
  int kb = blockIdx.x * 64, nb = blockIdx.y * 64;
  int lr = threadIdx.x >> 4, lc = (threadIdx.x & 15) * 4;
#pragma unroll
  for (int p = 0; p < 4; ++p) {
    int k = lr + p * 16;
    float4 v = *(const float4*)(ip + (size_t)(kb + k) * Ccols + nb + lc);
    t[k][lc + 0] = v.x; t[k][lc + 1] = v.y; t[k][lc + 2] = v.z; t[k][lc + 3] = v.w;
  }
  __syncthreads();
#pragma unroll
  for (int p = 0; p < 4; ++p) {
    int n = lr + p * 16;
    uint2 pk;
    pk.x = (u32)f2bf(t[lc + 0][n]) | ((u32)f2bf(t[lc + 1][n]) << 16);
    pk.y = (u32)f2bf(t[lc + 2][n]) | ((u32)f2bf(t[lc + 3][n]) << 16);
    *(uint2*)(op + (size_t)(nb + n) * R + kb + lc) = pk;
  }
}

// ---------------- CSR build ----------------
__global__ __launch_bounds__(256) void csr_hist(const int* __restrict__ dst,
                                                int* __restrict__ hist, int ne) {
  int e = blockIdx.x * 256 + threadIdx.x;
  if (e < ne) atomicAdd(&hist[dst[e]], 1);
}
__global__ __launch_bounds__(1024) void scan1(const int* __restrict__ in,
                                              int* __restrict__ out1, int* __restrict__ bsum, int n) {
  __shared__ int s[1024];
  int i = blockIdx.x * 1024 + threadIdx.x;
  int v = (i < n) ? in[i] : 0;
  s[threadIdx.x] = v; __syncthreads();
  for (int off = 1; off < 1024; off <<= 1) {
    int t = (threadIdx.x >= (u32)off) ? s[threadIdx.x - off] : 0;
    __syncthreads();
    s[threadIdx.x] += t;
    __syncthreads();
  }
  if (i < n) out1[i] = s[threadIdx.x];
  if (threadIdx.x == 1023) bsum[blockIdx.x] = s[1023];
}
__global__ __launch_bounds__(128) void scan2(int* __restrict__ bsum, int nb) {
  __shared__ int s[128];
  int v = (threadIdx.x < (u32)nb) ? bsum[threadIdx.x] : 0;
  s[threadIdx.x] = v; __syncthreads();
  for (int off = 1; off < 128; off <<= 1) {
    int t = (threadIdx.x >= (u32)off) ? s[threadIdx.x - off] : 0;
    __syncthreads();
    s[threadIdx.x] += t;
    __syncthreads();
  }
  if (threadIdx.x < (u32)nb) bsum[threadIdx.x] = threadIdx.x ? s[threadIdx.x - 1] : 0;
}
__global__ __launch_bounds__(256) void scan3(int* __restrict__ offs,
                                             const int* __restrict__ bsum, int n) {
  int i = blockIdx.x * 256 + threadIdx.x;
  if (i == 0) offs[0] = 0;
  if (i < n) offs[1 + i] += bsum[i >> 10];
}
__global__ __launch_bounds__(256) void csr_scatter(const int* __restrict__ dst,
                                                   int* __restrict__ cursor,
                                                   const int* __restrict__ offs,
                                                   int* __restrict__ eid, int ne) {
  int e = blockIdx.x * 256 + threadIdx.x;
  if (e < ne) {
    int d = dst[e];
    int p = offs[d] + atomicAdd(&cursor[d], 1);
    eid[p] = e;
  }
}
__global__ __launch_bounds__(256) void inv_perm(const int* __restrict__ eid,
                                                int* __restrict__ pos, int n) {
  int i = blockIdx.x * 256 + threadIdx.x;
  if (i < n) pos[eid[i]] = i;
}
__global__ __launch_bounds__(256) void remap_k(const int* __restrict__ idx,
                                               const int* __restrict__ map,
                                               int* __restrict__ out, int n) {
  int i = blockIdx.x * 256 + threadIdx.x;
  if (i < n) out[i] = map[idx[i]];
}
__global__ __launch_bounds__(256) void compose_src(const int* __restrict__ eid,
                                                   const int* __restrict__ srcv,
                                                   const int* __restrict__ map,
                                                   int* __restrict__ out, int n) {
  int i = blockIdx.x * 256 + threadIdx.x;
  if (i < n) {
    int s = srcv[eid[i]];
    out[i] = map ? map[s] : s;
  }
}

// ---------------- embeddings ----------------
__global__ __launch_bounds__(256) void embed_s1(
    const float* __restrict__ xin, const float* __restrict__ W1,
    const float* __restrict__ b1, const float* __restrict__ ln1,
    u16* __restrict__ t1, int rows, int bins, float vmin, float vmax,
    const int* __restrict__ perm) {
  int row = (blockIdx.x * 256 + threadIdx.x) >> 6;
  if (row >= rows) return;
  int lane = threadIdx.x & 63;
  float xv = xin[row];
  float rng = vmax - vmin;
  float step = rng / (float)(bins - 1);
  float gamma = 0.5f * ((float)bins / rng) * ((float)bins / rng);
  float rb = 0.f, rb2 = 0.f;
  if (lane < bins) {
    float d = xv - (vmin + lane * step);
    rb = __expf(-gamma * d * d);
  }
  if (bins > 64 && lane < bins - 64) {
    float d = xv - (vmin + (lane + 64) * step);
    rb2 = __expf(-gamma * d * d);
  }
  float u = b1[lane];
  int k1 = bins < 64 ? bins : 64;
  for (int k = 0; k < k1; ++k) {
    float rv = __shfl(rb, k, 64);
    u = fmaf(rv, W1[k * 64 + lane], u);
  }
  for (int k = 64; k < bins; ++k) {
    float rv = __shfl(rb2, k - 64, 64);
    u = fmaf(rv, W1[k * 64 + lane], u);
  }
  float s = wsum64(u), s2 = wsum64(u * u);
  float m = s * (1.f / 64.f), var = s2 * (1.f / 64.f) - m * m;
  float t = (u - m) * rsqrtf(var + 1e-5f) * ln1[lane] + ln1[64 + lane];
  int orow = perm ? perm[row] : row;
  t1[(size_t)orow * 64 + lane] = f2bf(t * sigm(t));
}

__global__ __launch_bounds__(256) void ln_silu(u16* __restrict__ buf,
                                               const float* __restrict__ ln, int rows) {
  int row = (blockIdx.x * 256 + threadIdx.x) >> 6;
  if (row >= rows) return;
  int lane = threadIdx.x & 63;
  int f = lane * 4;
  float v[4];
  up4(*(const uint2*)(buf + (size_t)row * 256 + f), v);
  float s = wsum64(v[0] + v[1] + v[2] + v[3]);
  float s2 = wsum64(v[0] * v[0] + v[1] * v[1] + v[2] * v[2] + v[3] * v[3]);
  float m = s * (1.f / 256.f);
  float rs = rsqrtf(s2 * (1.f / 256.f) - m * m + 1e-5f);
  float o[4];
#pragma unroll
  for (int k = 0; k < 4; ++k) {
    float t = (v[k] - m) * rs * ln[f + k] + ln[256 + f + k];
    o[k] = t * sigm(t);
  }
  *(uint2*)(buf + (size_t)row * 256 + f) = pk4(o);
}

__global__ __launch_bounds__(256) void atom_embed_kernel(
    const float* __restrict__ af, const float* __restrict__ W,
    const float* __restrict__ b, const float* __restrict__ ln,
    u16* __restrict__ out, int rows) {
  int row = blockIdx.x;
  if (row >= rows) return;
  __shared__ float a_s[92];
  __shared__ float red[8];
  int tid = threadIdx.x;
  if (tid < 92) a_s[tid] = af[(size_t)row * 92 + tid];
  __syncthreads();
  float v = b[tid];
#pragma unroll 4
  for (int k = 0; k < 92; ++k) v = fmaf(a_s[k], W[k * 256 + tid], v);
  float s = wsum64(v), s2 = wsum64(v * v);
  int lane = tid & 63, wid = tid >> 6;
  if (lane == 0) { red[wid] = s; red[4 + wid] = s2; }
  __syncthreads();
  s = red[0] + red[1] + red[2] + red[3];
  s2 = red[4] + red[5] + red[6] + red[7];
  float m = s * (1.f / 256.f), var = s2 * (1.f / 256.f) - m * m;
  float t = (v - m) * rsqrtf(var + 1e-5f) * ln[tid] + ln[256 + tid];
  out[(size_t)row * 256 + tid] = f2bf(t * sigm(t));
}

// ---------------- MFMA GEMM: C[M,ldc](bf16) = A[M,K](bf16) @ W + bias ----------------
__global__ __launch_bounds__(256) void mfma_gemm(
    const u16* __restrict__ A, const u16* __restrict__ Wt,
    const float* __restrict__ bias, u16* __restrict__ C,
    int M, int K, int ldc, u32 smap) {
  int bm = blockIdx.x * 128;
  if (bm >= M) return;
  int bn = blockIdx.y * 128;
  int slab = (smap >> ((bn >> 8) * 8)) & 0xFF;
  const u16* Wp = Wt + (size_t)slab * 256 * K + (size_t)(bn & 255) * K;
  const float* bp = bias + slab * 256 + (bn & 255);
  int tid = threadIdx.x;
  int w = tid >> 6, lane = tid & 63;
  int q = lane >> 4, r = lane & 15;
  int m0 = (w & 1) * 64;
  int n0 = (w >> 1) * 64;
  const u16* aptr[4];
#pragma unroll
  for (int mi = 0; mi < 4; ++mi) {
    int m = bm + m0 + mi * 16 + r;
    m = m < M - 1 ? m : M - 1;
    aptr[mi] = A + (size_t)m * K + q * 8;
  }
  const u16* wptr[4];
#pragma unroll
  for (int ni = 0; ni < 4; ++ni)
    wptr[ni] = Wp + (size_t)(n0 + ni * 16 + r) * K + q * 8;
  f32x4 acc[4][4] = {};
  for (int kb = 0; kb < K; kb += 32) {
    short8 bfr[4], afr[4];
#pragma unroll
    for (int mi = 0; mi < 4; ++mi) bfr[mi] = *(const short8*)(aptr[mi] + kb);
#pragma unroll
    for (int ni = 0; ni < 4; ++ni) afr[ni] = *(const short8*)(wptr[ni] + kb);
#pragma unroll
    for (int mi = 0; mi < 4; ++mi)
#pragma unroll
      for (int ni = 0; ni < 4; ++ni)
        acc[mi][ni] = __builtin_amdgcn_mfma_f32_16x16x32_bf16(afr[ni], bfr[mi],
                                                              acc[mi][ni], 0, 0, 0);
  }
#pragma unroll
  for (int mi = 0; mi < 4; ++mi) {
    int m = bm + m0 + mi * 16 + r;
    if (m < M) {
#pragma unroll
      for (int ni = 0; ni < 4; ++ni) {
        int n = n0 + ni * 16 + q * 4;
        float4 bv = *(const float4*)(bp + n);
        uint2 o;
        o.x = (u32)f2bf(acc[mi][ni].x + bv.x) | ((u32)f2bf(acc[mi][ni].y + bv.y) << 16);
        o.y = (u32)f2bf(acc[mi][ni].z + bv.z) | ((u32)f2bf(acc[mi][ni].w + bv.w) << 16);
        *(uint2*)(C + (size_t)m * ldc + bn + n) = o;
      }
    }
  }
}

// ---------------- mega_line: 16 dst, 512 thr; quarter-wave Phase C (r13 structure) ------
__global__ __launch_bounds__(512) void mega_line(
    u16* __restrict__ h, u16* __restrict__ e, const u16* __restrict__ G0Bh,
    const u16* __restrict__ Wt13, const float* __restrict__ b13,
    const u16* __restrict__ Wt2, const float* __restrict__ b2v,
    const int* __restrict__ src_perm, const int* __restrict__ offs,
    const float* __restrict__ lnS, const float* __restrict__ lnB, int nn) {
  __shared__ u16 g1ah[16][520];
  __shared__ u16 pe[64][264];
  __shared__ int oloc[17];
  int tid = threadIdx.x;
  int w = tid >> 6, lane = tid & 63;
  int q = lane >> 4, r = lane & 15;
  int v0 = blockIdx.x * 16;
  if (tid < 17) { int v = v0 + tid; oloc[tid] = offs[v < nn ? v : nn]; }
  // ---- Phase A: g1ah[16][512] = h[v0..v0+16) @ [W1|W3] + b ----
  {
    int mrow = v0 + r; if (mrow > nn - 1) mrow = nn - 1;
    const u16* arow = h + (size_t)mrow * 256 + q * 8;
    f32x4 acc[4] = {};
    for (int kb = 0; kb < 256; kb += 32) {
      short8 af = *(const short8*)(arow + kb);
#pragma unroll
      for (int t = 0; t < 4; ++t) {
        int ng = (4 * w + t) * 16 + r;
        const u16* wrow = Wt13 + (size_t)(ng >> 8) * 2 * 65536 +
                          (size_t)(ng & 255) * 256 + q * 8;
        short8 wf = *(const short8*)(wrow + kb);
        acc[t] = __builtin_amdgcn_mfma_f32_16x16x32_bf16(wf, af, acc[t], 0, 0, 0);
      }
    }
#pragma unroll
    for (int t = 0; t < 4; ++t) {
      int nb = (4 * w + t) * 16 + q * 4;
      const float* bp = b13 + (nb >> 8) * 2 * 256 + (nb & 255);
      float o[4] = {acc[t].x + bp[0], acc[t].y + bp[1], acc[t].z + bp[2], acc[t].w + bp[3]};
      *(uint2*)&g1ah[r][nb] = pk4(o);
    }
  }
  __syncthreads();
  int gl = lane & 15;
  int qg = lane >> 4;
  int dd = w * 2 + (qg >> 1);
  int half = qg & 1;
  int vv = v0 + dd;
  int fa = gl * 8;
  int fB = 128 + gl * 8;
  int r0 = oloc[0], r1 = oloc[16];
  int d0 = oloc[dd], d1 = oloc[dd + 1];
  float lwe[16], lbe[16];
#pragma unroll
  for (int k = 0; k < 8; ++k) {
    lwe[k] = lnS[fa + k];     lbe[k] = lnB[fa + k];
    lwe[8 + k] = lnS[fB + k]; lbe[8 + k] = lnB[fB + k];
  }
  uint4 g1p0 = *(const uint4*)&g1ah[dd][fa];
  uint4 g1p1 = *(const uint4*)&g1ah[dd][fB];
  float ssh[16] = {}, ssm[16] = {};

  for (int ec = r0; ec < r1; ec += 64) {
    // ---- Phase B: pe[0..64) = e[ec..ec+64) @ W2 + b2 ----
    {
      const u16* w0p = Wt2 + (size_t)((2 * w) * 16 + r) * 256 + q * 8;
      const u16* w1p = Wt2 + (size_t)((2 * w + 1) * 16 + r) * 256 + q * 8;
      f32x4 acc[4][2] = {};
      for (int kb = 0; kb < 256; kb += 32) {
        short8 wf0 = *(const short8*)(w0p + kb);
        short8 wf1 = *(const short8*)(w1p + kb);
#pragma unroll
        for (int mt = 0; mt < 4; ++mt) {
          int erow = ec + mt * 16 + r;
          if (erow > r1 - 1) erow = r1 - 1;
          short8 af = *(const short8*)(e + (size_t)erow * 256 + kb + q * 8);
          acc[mt][0] = __builtin_amdgcn_mfma_f32_16x16x32_bf16(wf0, af, acc[mt][0], 0, 0, 0);
          acc[mt][1] = __builtin_amdgcn_mfma_f32_16x16x32_bf16(wf1, af, acc[mt][1], 0, 0, 0);
        }
      }
#pragma unroll
      for (int mt = 0; mt < 4; ++mt)
#pragma unroll
        for (int nt = 0; nt < 2; ++nt) {
          int nb = (2 * w + nt) * 16 + q * 4;
          float o[4] = {acc[mt][nt].x + b2v[nb], acc[mt][nt].y + b2v[nb + 1],
                        acc[mt][nt].z + b2v[nb + 2], acc[mt][nt].w + b2v[nb + 3]};
          *(uint2*)&pe[mt * 16 + r][nb] = pk4(o);
        }
    }
    __syncthreads();
    // ---- Phase C: quarter-wave per dst-half, stride-2 walk ----
    {
      int ce = ec + 64 < r1 ? ec + 64 : r1;
      int i0 = d0 > ec ? d0 : ec;
      int i1 = d1 < ce ? d1 : ce;
      int is = i0 + half;
      if (is < i1) {
        int sv = src_perm[is];
        uint4 pg0a = *(const uint4*)(G0Bh + (size_t)sv * 512 + fa);
        uint4 pg0b = *(const uint4*)(G0Bh + (size_t)sv * 512 + fB);
        uint4 pbha = *(const uint4*)(G0Bh + (size_t)sv * 512 + 256 + fa);
        uint4 pbhb = *(const uint4*)(G0Bh + (size_t)sv * 512 + 256 + fB);
        for (int i = is; i < i1; i += 2) {
          uint4 cg0a = pg0a, cg0b = pg0b, cbha = pbha, cbhb = pbhb;
          if (i + 2 < i1) {
            int sv2 = src_perm[i + 2];
            pg0a = *(const uint4*)(G0Bh + (size_t)sv2 * 512 + fa);
            pg0b = *(const uint4*)(G0Bh + (size_t)sv2 * 512 + fB);
            pbha = *(const uint4*)(G0Bh + (size_t)sv2 * 512 + 256 + fa);
            pbhb = *(const uint4*)(G0Bh + (size_t)sv2 * 512 + 256 + fB);
          }
          float g0[16], bh[16], pv[16], ev[16], g1v[16];
          up8(cg0a, g0); up8(cg0b, g0 + 8);
          up8(cbha, bh); up8(cbhb, bh + 8);
          up8(*(const uint4*)&pe[i - ec][fa], pv);
          up8(*(const uint4*)&pe[i - ec][fB], pv + 8);
          up8(*(const uint4*)(e + (size_t)i * 256 + fa), ev);
          up8(*(const uint4*)(e + (size_t)i * 256 + fB), ev + 8);
          up8(g1p0, g1v); up8(g1p1, g1v + 8);
          float t[16];
          float ssum = 0.f, s2sum = 0.f;
#pragma unroll
          for (int k = 0; k < 16; ++k) {
            float sg = sigm(g0[k] + g1v[k] + pv[k]);
            t[k] = sg * ev[k];
            ssh[k] = fmaf(bh[k], sg, ssh[k]);
            ssm[k] += sg;
            ssum += t[k]; s2sum += t[k] * t[k];
          }
          float s1 = wsum16(ssum), s2 = wsum16(s2sum);
          float mn = s1 * (1.f / 256.f);
          float rs = rsqrtf(s2 * (1.f / 256.f) - mn * mn + 1e-5f);
          float o[16];
#pragma unroll
          for (int k = 0; k < 16; ++k) o[k] = (t[k] - mn) * rs * lwe[k] + lbe[k];
          *(uint4*)(e + (size_t)i * 256 + fa) = pk8(o);
          *(uint4*)(e + (size_t)i * 256 + fB) = pk8(o + 8);
        }
      }
    }
    __syncthreads();
  }
  // ---- merge halves + Phase D ----
#pragma unroll
  for (int k = 0; k < 16; ++k) {
    ssh[k] += __shfl_xor(ssh[k], 16, 64);
    ssm[k] += __shfl_xor(ssm[k], 16, 64);
  }
  if (half == 0 && vv < nn) {
    float ah[16], tt[16];
    up8(*(const uint4*)&g1ah[dd][256 + fa], ah);
    up8(*(const uint4*)&g1ah[dd][256 + fB], ah + 8);
    float ssum = 0.f, s2sum = 0.f;
#pragma unroll
    for (int k = 0; k < 16; ++k) {
      tt[k] = ah[k] + ssh[k] / (ssm[k] + 1e-8f);
      ssum += tt[k]; s2sum += tt[k] * tt[k];
    }
    float s1 = wsum16(ssum), s2 = wsum16(s2sum);
    float mn = s1 * (1.f / 256.f);
    float rs = rsqrtf(s2 * (1.f / 256.f) - mn * mn + 1e-5f);
    float o[16];
#pragma unroll
    for (int k = 0; k < 8; ++k) {
      o[k] = (tt[k] - mn) * rs * lnS[256 + fa + k] + lnB[256 + fa + k];
      o[8 + k] = (tt[8 + k] - mn) * rs * lnS[256 + fB + k] + lnB[256 + fB + k];
    }
    *(uint4*)(h + (size_t)vv * 256 + fa) = pk8(o);
    *(uint4*)(h + (size_t)vv * 256 + fB) = pk8(o + 8);
  }
}

// ---------------- mega_atom v2: 8 dst, 256 thr; NO inner GEMM, NO loop barriers ----------
__global__ __launch_bounds__(256) void mega_atom(
    u16* __restrict__ h, u16* __restrict__ e, const u16* __restrict__ GAll,
    const u16* __restrict__ Pe,
    const int* __restrict__ src_perm, const int* __restrict__ offs,
    const float* __restrict__ lnS, const float* __restrict__ lnB, int nn) {
  __shared__ int oloc[9];
  int tid = threadIdx.x;
  int w = tid >> 6, lane = tid & 63;
  int v0 = blockIdx.x * 8;
  if (tid < 9) { int v = v0 + tid; oloc[tid] = offs[v < nn ? v : nn]; }
  __syncthreads();
  int gl = lane & 15;
  int qg = lane >> 4;
  int dd = w * 2 + (qg >> 1);
  int half = qg & 1;
  int vv = v0 + dd;
  int fa = gl * 8;
  int fB = 128 + gl * 8;
  int d0 = oloc[dd], d1 = oloc[dd + 1];
  float lwe[16], lbe[16];
#pragma unroll
  for (int k = 0; k < 8; ++k) {
    lwe[k] = lnS[fa + k];     lbe[k] = lnB[fa + k];
    lwe[8 + k] = lnS[fB + k]; lbe[8 + k] = lnB[fB + k];
  }
  int vc = vv < nn ? vv : nn - 1;
  uint4 g1p0 = *(const uint4*)(GAll + (size_t)vc * 1024 + 256 + fa);
  uint4 g1p1 = *(const uint4*)(GAll + (size_t)vc * 1024 + 256 + fB);
  float ssh[16] = {}, ssm[16] = {};

  int is = d0 + half;
  if (is < d1) {
    int sv = src_perm[is];
    uint4 pg0a = *(const uint4*)(GAll + (size_t)sv * 1024 + fa);
    uint4 pg0b = *(const uint4*)(GAll + (size_t)sv * 1024 + fB);
    uint4 pbha = *(const uint4*)(GAll + (size_t)sv * 1024 + 768 + fa);
    uint4 pbhb = *(const uint4*)(GAll + (size_t)sv * 1024 + 768 + fB);
    for (int i = is; i < d1; i += 2) {
      uint4 cg0a = pg0a, cg0b = pg0b, cbha = pbha, cbhb = pbhb;
      if (i + 2 < d1) {
        int sv2 = src_perm[i + 2];
        pg0a = *(const uint4*)(GAll + (size_t)sv2 * 1024 + fa);
        pg0b = *(const uint4*)(GAll + (size_t)sv2 * 1024 + fB);
        pbha = *(const uint4*)(GAll + (size_t)sv2 * 1024 + 768 + fa);
        pbhb = *(const uint4*)(GAll + (size_t)sv2 * 1024 + 768 + fB);
      }
      float g0[16], bh[16], pv[16], ev[16], g1v[16];
      up8(cg0a, g0); up8(cg0b, g0 + 8);
      up8(cbha, bh); up8(cbhb, bh + 8);
      up8(*(const uint4*)(Pe + (size_t)i * 256 + fa), pv);
      up8(*(const uint4*)(Pe + (size_t)i * 256 + fB), pv + 8);
      up8(*(const uint4*)(e + (size_t)i * 256 + fa), ev);
      up8(*(const uint4*)(e + (size_t)i * 256 + fB), ev + 8);
      up8(g1p0, g1v); up8(g1p1, g1v + 8);
      float t[16];
      float ssum = 0.f, s2sum = 0.f;
#pragma unroll
      for (int k = 0; k < 16; ++k) {
        float sg = sigm(g0[k] + g1v[k] + pv[k]);
        t[k] = sg * ev[k];
        ssh[k] = fmaf(bh[k], sg, ssh[k]);
        ssm[k] += sg;
        ssum += t[k]; s2sum += t[k] * t[k];
      }
      float s1 = wsum16(ssum), s2 = wsum16(s2sum);
      float mn = s1 * (1.f / 256.f);
      float rs = rsqrtf(s2 * (1.f / 256.f) - mn * mn + 1e-5f);
      float o[16];
#pragma unroll
      for (int k = 0; k < 16; ++k) o[k] = (t[k] - mn) * rs * lwe[k] + lbe[k];
      *(uint4*)(e + (size_t)i * 256 + fa) = pk8(o);
      *(uint4*)(e + (size_t)i * 256 + fB) = pk8(o + 8);
    }
  }
  // ---- merge halves + node update ----
#pragma unroll
  for (int k = 0; k < 16; ++k) {
    ssh[k] += __shfl_xor(ssh[k], 16, 64);
    ssm[k] += __shfl_xor(ssm[k], 16, 64);
  }
  if (half == 0 && vv < nn) {
    float ah[16], tt[16];
    up8(*(const uint4*)(GAll + (size_t)vv * 1024 + 512 + fa), ah);
    up8(*(const uint4*)(GAll + (size_t)vv * 1024 + 512 + fB), ah + 8);
    float ssum = 0.f, s2sum = 0.f;
#pragma unroll
    for (int k = 0; k < 16; ++k) {
      tt[k] = ah[k] + ssh[k] / (ssm[k] + 1e-8f);
      ssum += tt[k]; s2sum += tt[k] * tt[k];
    }
    float s1 = wsum16(ssum), s2 = wsum16(s2sum);
    float mn = s1 * (1.f / 256.f);
    float rs = rsqrtf(s2 * (1.f / 256.f) - mn * mn + 1e-5f);
    float o[16];
#pragma unroll
    for (int k = 0; k < 8; ++k) {
      o[k] = (tt[k] - mn) * rs * lnS[256 + fa + k] + lnB[256 + fa + k];
      o[8 + k] = (tt[8 + k] - mn) * rs * lnS[256 + fB + k] + lnB[256 + fB + k];
    }
    *(uint4*)(h + (size_t)vv * 256 + fa) = pk8(o);
    *(uint4*)(h + (size_t)vv * 256 + fB) = pk8(o + 8);
  }
}

// ---------------- readout ----------------
__global__ __launch_bounds__(256) void pool_acc(
    const u16* __restrict__ x, const int* __restrict__ gid,
    float* __restrict__ out, float* __restrict__ cnt, int n) {
  int v = (blockIdx.x * 256 + threadIdx.x) >> 6;
  if (v >= n) return;
  int lane = threadIdx.x & 63;
  int f = lane * 4;
  int g = gid[v];
  float xv[4];
  up4(*(const uint2*)(x + (size_t)v * 256 + f), xv);
  float* p = out + (size_t)g * 256 + f;
  unsafeAtomicAdd(p + 0, xv[0]);
  unsafeAtomicAdd(p + 1, xv[1]);
  unsafeAtomicAdd(p + 2, xv[2]);
  unsafeAtomicAdd(p + 3, xv[3]);
  if (lane == 0) unsafeAtomicAdd(cnt + g, 1.0f);
}
__global__ __launch_bounds__(256) void pool_div(float* __restrict__ out,
                                                const float* __restrict__ cnt, int n) {
  int i = blockIdx.x * blockDim.x + threadIdx.x;
  if (i < n) out[i] /= fmaxf(cnt[i >> 8], 1.0f);
}

// ---------------- host ----------------
extern "C" void kernel_launch(void* const* d_in, const int* in_sizes, int n_in,
                              void* d_out, int out_size, void* d_ws, size_t ws_size,
                              hipStream_t stream) {
  const float* atom_features = (const float*)d_in[0];
  const float* bondlength    = (const float*)d_in[1];
  const float* angle_h       = (const float*)d_in[2];
  const int*   src           = (const int*)d_in[3];
  const int*   dst           = (const int*)d_in[4];
  const int*   lg_src        = (const int*)d_in[5];
  const int*   lg_dst        = (const int*)d_in[6];
  const int*   gid           = (const int*)d_in[7];
  const float* atom_W  = (const float*)d_in[8];
  const float* atom_b  = (const float*)d_in[9];
  const float* atom_ln = (const float*)d_in[10];
  const float* edge_W1 = (const float*)d_in[11];
  const float* edge_b1 = (const float*)d_in[12];
  const float* edge_ln1= (const float*)d_in[13];
  const float* edge_W2 = (const float*)d_in[14];
  const float* edge_b2 = (const float*)d_in[15];
  const float* edge_ln2= (const float*)d_in[16];
  const float* ang_W1  = (const float*)d_in[17];
  const float* ang_b1  = (const float*)d_in[18];
  const float* ang_ln1 = (const float*)d_in[19];
  const float* ang_W2  = (const float*)d_in[20];
  const float* ang_b2  = (const float*)d_in[21];
  const float* ang_ln2 = (const float*)d_in[22];
  const float* conv_W  = (const float*)d_in[23];
  const float* conv_b  = (const float*)d_in[24];
  const float* conv_lns= (const float*)d_in[25];
  const float* conv_lnb= (const float*)d_in[26];

  int N = in_sizes[0] / 92;
  int E = in_sizes[1];
  int T = in_sizes[2];

  // ---- workspace layout ----
  char* ws = (char*)d_ws;
  size_t o = 0;
  auto alloc = [&](size_t bytes) { size_t r = o; o = (o + bytes + 255) & ~(size_t)255; return r; };
  u16* z     = (u16*)(ws + alloc((size_t)T * 512));
  u16* y     = (u16*)(ws + alloc((size_t)E * 512));
  u16* x     = (u16*)(ws + alloc((size_t)N * 512));
  int* offsL = (int*)(ws + alloc((size_t)(E + 1) * 4));
  int* offsA = (int*)(ws + alloc((size_t)(N + 1) * 4));
  int* spL   = (int*)(ws + alloc((size_t)T * 4));
  int* spA   = (int*)(ws + alloc((size_t)E * 4));
  int* pA    = (int*)(ws + alloc((size_t)E * 4));
  int* pL    = (int*)(ws + alloc((size_t)T * 4));
  int* eidL  = (int*)(ws + alloc((size_t)T * 4));
  int* eidA  = (int*)(ws + alloc((size_t)E * 4));
  int* ldSt  = (int*)(ws + alloc((size_t)T * 4));
  int* tmp   = (int*)(ws + alloc((size_t)(E > N ? E : N) * 4));
  int* bsum  = (int*)(ws + alloc(1024));
  float* cnt = (float*)(ws + alloc(1024));
  u16* WtAll = (u16*)(ws + alloc((size_t)12 * 5 * 65536 * 2));
  u16* WtAng = (u16*)(ws + alloc((size_t)16384 * 2));
  u16* WtEdg = (u16*)(ws + alloc((size_t)16384 * 2));
  size_t scratch_base = o;
  size_t need = scratch_base + (size_t)E * 1024;  // line: G0Bh (82 MB) dominant
  {
    size_t atom_need = scratch_base + (size_t)N * 2048 + (size_t)E * 512;  // GAll + PeA
    if (atom_need > need) need = atom_need;
    size_t embed_need = scratch_base + ((size_t)T + E) * 128;
    if (embed_need > need) need = embed_need;
  }
  if (ws_size < need) {
    fill_kernel<<<(out_size + 255) / 256, 256, 0, stream>>>(
        (float*)d_out, out_size, (float)(ws_size >> 20));
    return;
  }

  // ---- weight transposes ----
  wtrans<<<dim3(4, 4, 60), 256, 0, stream>>>(conv_W, WtAll, 256, 256);
  wtrans<<<dim3(1, 4, 1), 256, 0, stream>>>(ang_W2, WtAng, 64, 256);
  wtrans<<<dim3(1, 4, 1), 256, 0, stream>>>(edge_W2, WtEdg, 64, 256);

  // ---- CSR + permutations ----
  auto build_csr = [&](const int* dvec, int ne_, int nn_, int* offs_, int* eid_) {
    hipMemsetAsync(tmp, 0, (size_t)nn_ * 4, stream);
    csr_hist<<<(ne_ + 255) / 256, 256, 0, stream>>>(dvec, tmp, ne_);
    int nb = (nn_ + 1023) / 1024;
    scan1<<<nb, 1024, 0, stream>>>(tmp, offs_ + 1, bsum, nn_);
    scan2<<<1, 128, 0, stream>>>(bsum, nb);
    scan3<<<(nn_ + 255) / 256, 256, 0, stream>>>(offs_, bsum, nn_);
    hipMemsetAsync(tmp, 0, (size_t)nn_ * 4, stream);
    csr_scatter<<<(ne_ + 255) / 256, 256, 0, stream>>>(dvec, tmp, offs_, eid_, ne_);
  };
  build_csr(dst, E, N, offsA, eidA);
  inv_perm<<<(E + 255) / 256, 256, 0, stream>>>(eidA, pA, E);
  compose_src<<<(E + 255) / 256, 256, 0, stream>>>(eidA, src, nullptr, spA, E);
  remap_k<<<(T + 255) / 256, 256, 0, stream>>>(lg_dst, pA, ldSt, T);
  build_csr(ldSt, T, E, offsL, eidL);
  inv_perm<<<(T + 255) / 256, 256, 0, stream>>>(eidL, pL, T);
  compose_src<<<(T + 255) / 256, 256, 0, stream>>>(eidL, lg_src, pA, spL, T);

  // ---- embeddings ----
  u16* t1T = (u16*)(ws + scratch_base);
  u16* t1E = t1T + (size_t)T * 64;
  embed_s1<<<(T + 3) / 4, 256, 0, stream>>>(angle_h, ang_W1, ang_b1, ang_ln1,
                                            t1T, T, 40, -1.f, 1.f, pL);
  embed_s1<<<(E + 3) / 4, 256, 0, stream>>>(bondlength, edge_W1, edge_b1, edge_ln1,
                                            t1E, E, 80, 0.f, 8.f, pA);
  mfma_gemm<<<dim3((T + 127) / 128, 2), 256, 0, stream>>>(
      t1T, WtAng, ang_b2, z, T, 64, 256, 0u);
  mfma_gemm<<<dim3((E + 127) / 128, 2), 256, 0, stream>>>(
      t1E, WtEdg, edge_b2, y, E, 64, 256, 0u);
  ln_silu<<<(T + 3) / 4, 256, 0, stream>>>(z, ang_ln2, T);
  ln_silu<<<(E + 3) / 4, 256, 0, stream>>>(y, edge_ln2, E);
  atom_embed_kernel<<<N, 256, 0, stream>>>(atom_features, atom_W, atom_b, atom_ln, x, N);

  // ---- 12 EGGC layers ----
  for (int l = 0; l < 12; ++l) {
    const u16* WtL  = WtAll + (size_t)l * 5 * 65536;
    const float* bl = conv_b + (size_t)l * 5 * 256;
    const float* lnS = conv_lns + (size_t)l * 512;
    const float* lnB = conv_lnb + (size_t)l * 512;
    bool line = (l < 8) && ((l & 1) == 0);
    if (line) {
      u16* G0Bh = (u16*)(ws + scratch_base);
      mfma_gemm<<<dim3((E + 127) / 128, 4), 256, 0, stream>>>(
          y, WtL, bl, G0Bh, E, 256, 512, 0u | (4u << 8));
      mega_line<<<(E + 15) / 16, 512, 0, stream>>>(
          y, z, G0Bh, WtL + 65536, bl + 256, WtL + 2 * 65536, bl + 2 * 256,
          spL, offsL, lnS, lnB, E);
    } else {
      u16* GAll = (u16*)(ws + scratch_base);
      u16* PeA  = GAll + (size_t)N * 1024;
      mfma_gemm<<<dim3((N + 127) / 128, 8), 256, 0, stream>>>(
          x, WtL, bl, GAll, N, 256, 1024, 0u | (1u << 8) | (3u << 16) | (4u << 24));
      mfma_gemm<<<dim3((E + 127) / 128, 2), 256, 0, stream>>>(
          y, WtL + 2 * 65536, bl + 2 * 256, PeA, E, 256, 256, 0u);
      mega_atom<<<(N + 7) / 8, 256, 0, stream>>>(
          x, y, GAll, PeA, spA, offsA, lnS, lnB, N);
    }
  }

  // ---- readout ----
  hipMemsetAsync(d_out, 0, (size_t)out_size * sizeof(float), stream);
  hipMemsetAsync(cnt, 0, 256 * sizeof(float), stream);
  pool_acc<<<(N + 3) / 4, 256, 0, stream>>>(x, gid, (float*)d_out, cnt, N);
  pool_div<<<(out_size + 255) / 256, 256, 0, stream>>>((float*)d_out, cnt, out_size);
}